// Round 9
// baseline (220.627 us; speedup 1.0000x reference)
//
#include <hip/hip_runtime.h>
#include <math.h>

#define BATCH  32
#define CH     768
#define HW     3136       // 56*56
#define K2C    1536       // 2*CH
#define BN_EPS 1e-5f

typedef float fv4 __attribute__((ext_vector_type(4)));

// ---------------- K1: per-(b,c) avg + max pool, one wave per row ----------------
__global__ __launch_bounds__(256) void pool_kernel(const float* __restrict__ x,
                                                   float* __restrict__ avg,
                                                   float* __restrict__ mx) {
    const int wave = threadIdx.x >> 6, lane = threadIdx.x & 63;
    const int bc = blockIdx.x * 4 + wave;            // 0 .. B*C-1
    const fv4* row = (const fv4*)(x + (size_t)bc * HW);
    float s = 0.f, m = -INFINITY;
    for (int q = lane; q < HW / 4; q += 64) {        // 784 fv4 per row
        fv4 v = row[q];
        s += v.x + v.y + v.z + v.w;
        m = fmaxf(m, fmaxf(fmaxf(v.x, v.y), fmaxf(v.z, v.w)));
    }
    for (int off = 32; off; off >>= 1) {
        s += __shfl_down(s, off);
        m = fmaxf(m, __shfl_down(m, off));
    }
    if (lane == 0) {
        avg[bc] = s * (1.0f / (float)HW);
        mx[bc]  = m;
    }
}

// ---------------- K2: im = concat(avg,max) @ W^T + b, then BN ----------------
__global__ __launch_bounds__(256) void mlp_bn_kernel(const float* __restrict__ avg,
                                                     const float* __restrict__ mx,
                                                     const float* __restrict__ w,
                                                     const float* __restrict__ bias,
                                                     const float* __restrict__ gamma,
                                                     const float* __restrict__ beta,
                                                     const float* __restrict__ mean,
                                                     const float* __restrict__ var,
                                                     float* __restrict__ im) {
    const int b0 = blockIdx.x * 2, b1 = b0 + 1;
    const int t  = threadIdx.x;
    const int co = blockIdx.y * 16 + (t >> 4);       // output channel
    const int kp = t & 15;                           // k-part: 96 floats each
    const float* s0;
    const float* s1;
    if (kp < 8) {
        s0 = avg + b0 * CH + kp * 96;
        s1 = avg + b1 * CH + kp * 96;
    } else {
        s0 = mx + b0 * CH + (kp - 8) * 96;
        s1 = mx + b1 * CH + (kp - 8) * 96;
    }
    const fv4* wrow = (const fv4*)(w + (size_t)co * K2C + kp * 96);
    const fv4* v04  = (const fv4*)s0;
    const fv4* v14  = (const fv4*)s1;
    float a0 = 0.f, a1 = 0.f;
    #pragma unroll
    for (int j = 0; j < 24; ++j) {
        fv4 wv = wrow[j], u0 = v04[j], u1 = v14[j];
        a0 += wv.x * u0.x + wv.y * u0.y + wv.z * u0.z + wv.w * u0.w;
        a1 += wv.x * u1.x + wv.y * u1.y + wv.z * u1.z + wv.w * u1.w;
    }
    for (int off = 8; off; off >>= 1) {
        a0 += __shfl_down(a0, off);
        a1 += __shfl_down(a1, off);
    }
    if (kp == 0) {
        const float scale = gamma[co] * rsqrtf(var[co] + BN_EPS);
        const float base  = beta[co] - mean[co] * scale;
        im[b0 * CH + co] = (a0 + bias[co]) * scale + base;
        im[b1 * CH + co] = (a1 + bias[co]) * scale + base;
    }
}

// ---------------- K3: fused att + gate (round-5 structure) ----------------
// 256-thr block owns (b, 32 positions); 24 fv4/thread register payload;
// NT loads (x not reused through cache); NORMAL stores this round (A/B vs
// round 5's NT stores: let L2 writeback aggregate the 128B-chunk stream).
__global__ __launch_bounds__(256) void att_gate_kernel(const float* __restrict__ x,
                                                       const float* __restrict__ im,
                                                       float* __restrict__ out) {
    const int b    = blockIdx.y;
    const int p0   = blockIdx.x * 32;                // 32 positions = 8 quads
    const int t    = threadIdx.x;
    const int cg   = t >> 3;                         // 0..31
    const int pidx = t & 7;                          // 0..7

    __shared__ float im_s[CH];
    {
        const fv4* src = (const fv4*)(im + b * CH);
        fv4* dst = (fv4*)im_s;
        for (int i = t; i < CH / 4; i += 256) dst[i] = src[i];
    }

    const float* xb = x + (size_t)b * CH * HW + p0 + pidx * 4;

    fv4 v[24];
    #pragma unroll
    for (int j = 0; j < 24; ++j)
        v[j] = __builtin_nontemporal_load((const fv4*)(xb + (size_t)(cg + 32 * j) * HW));

    __syncthreads();                                 // im_s ready

    fv4 acc = {0.f, 0.f, 0.f, 0.f};
    #pragma unroll
    for (int j = 0; j < 24; ++j)
        acc += im_s[cg + 32 * j] * v[j];

    // intra-wave reduce: lanes 8 apart share pidx
    #pragma unroll
    for (int off = 8; off <= 32; off <<= 1) {
        acc.x += __shfl_down(acc.x, off);
        acc.y += __shfl_down(acc.y, off);
        acc.z += __shfl_down(acc.z, off);
        acc.w += __shfl_down(acc.w, off);
    }
    __shared__ fv4 part[4][8];                       // [wave][pidx]
    __shared__ fv4 att_s[8];
    const int wave = t >> 6, lane = t & 63;
    if (lane < 8) part[wave][lane] = acc;
    __syncthreads();
    if (t < 8) att_s[t] = part[0][t] + part[1][t] + part[2][t] + part[3][t];
    __syncthreads();

    const fv4 a4 = att_s[pidx];
    float* ob = out + (size_t)b * CH * HW + p0 + pidx * 4;
    #pragma unroll
    for (int j = 0; j < 24; ++j)
        *(fv4*)(ob + (size_t)(cg + 32 * j) * HW) = v[j] * a4;
}

extern "C" void kernel_launch(void* const* d_in, const int* in_sizes, int n_in,
                              void* d_out, int out_size, void* d_ws, size_t ws_size,
                              hipStream_t stream) {
    const float* x      = (const float*)d_in[0];
    const float* conv_w = (const float*)d_in[1];
    const float* conv_b = (const float*)d_in[2];
    const float* gamma  = (const float*)d_in[3];
    const float* beta   = (const float*)d_in[4];
    const float* mean   = (const float*)d_in[5];
    const float* var    = (const float*)d_in[6];
    float* out = (float*)d_out;

    float* ws  = (float*)d_ws;
    float* avg = ws;                    // B*C = 24576
    float* mx  = ws + 24576;            // B*C
    float* im  = ws + 49152;            // B*C

    pool_kernel<<<(BATCH * CH) / 4, 256, 0, stream>>>(x, avg, mx);
    mlp_bn_kernel<<<dim3(BATCH / 2, CH / 16), 256, 0, stream>>>(avg, mx, conv_w, conv_b,
                                                                gamma, beta, mean, var, im);
    att_gate_kernel<<<dim3(HW / 32, BATCH), 256, 0, stream>>>(x, im, out);
}

// Round 10
// 174.925 us; speedup vs baseline: 1.2613x; 1.2613x over previous
//
#include <hip/hip_runtime.h>
#include <math.h>

#define BATCH  32
#define CH     768
#define HW     3136       // 56*56
#define K2C    1536       // 2*CH
#define BN_EPS 1e-5f

typedef float fv4 __attribute__((ext_vector_type(4)));

// ---------------- K1: per-(b,c) avg + max pool, one wave per row ----------------
__global__ __launch_bounds__(256) void pool_kernel(const float* __restrict__ x,
                                                   float* __restrict__ avg,
                                                   float* __restrict__ mx) {
    const int wave = threadIdx.x >> 6, lane = threadIdx.x & 63;
    const int bc = blockIdx.x * 4 + wave;            // 0 .. B*C-1
    const fv4* row = (const fv4*)(x + (size_t)bc * HW);
    float s = 0.f, m = -INFINITY;
    for (int q = lane; q < HW / 4; q += 64) {        // 784 fv4 per row
        fv4 v = row[q];
        s += v.x + v.y + v.z + v.w;
        m = fmaxf(m, fmaxf(fmaxf(v.x, v.y), fmaxf(v.z, v.w)));
    }
    for (int off = 32; off; off >>= 1) {
        s += __shfl_down(s, off);
        m = fmaxf(m, __shfl_down(m, off));
    }
    if (lane == 0) {
        avg[bc] = s * (1.0f / (float)HW);
        mx[bc]  = m;
    }
}

// ---------------- K2: im = concat(avg,max) @ W^T + b, then BN ----------------
__global__ __launch_bounds__(256) void mlp_bn_kernel(const float* __restrict__ avg,
                                                     const float* __restrict__ mx,
                                                     const float* __restrict__ w,
                                                     const float* __restrict__ bias,
                                                     const float* __restrict__ gamma,
                                                     const float* __restrict__ beta,
                                                     const float* __restrict__ mean,
                                                     const float* __restrict__ var,
                                                     float* __restrict__ im) {
    const int b0 = blockIdx.x * 2, b1 = b0 + 1;
    const int t  = threadIdx.x;
    const int co = blockIdx.y * 16 + (t >> 4);       // output channel
    const int kp = t & 15;                           // k-part: 96 floats each
    const float* s0;
    const float* s1;
    if (kp < 8) {
        s0 = avg + b0 * CH + kp * 96;
        s1 = avg + b1 * CH + kp * 96;
    } else {
        s0 = mx + b0 * CH + (kp - 8) * 96;
        s1 = mx + b1 * CH + (kp - 8) * 96;
    }
    const fv4* wrow = (const fv4*)(w + (size_t)co * K2C + kp * 96);
    const fv4* v04  = (const fv4*)s0;
    const fv4* v14  = (const fv4*)s1;
    float a0 = 0.f, a1 = 0.f;
    #pragma unroll
    for (int j = 0; j < 24; ++j) {
        fv4 wv = wrow[j], u0 = v04[j], u1 = v14[j];
        a0 += wv.x * u0.x + wv.y * u0.y + wv.z * u0.z + wv.w * u0.w;
        a1 += wv.x * u1.x + wv.y * u1.y + wv.z * u1.z + wv.w * u1.w;
    }
    for (int off = 8; off; off >>= 1) {
        a0 += __shfl_down(a0, off);
        a1 += __shfl_down(a1, off);
    }
    if (kp == 0) {
        const float scale = gamma[co] * rsqrtf(var[co] + BN_EPS);
        const float base  = beta[co] - mean[co] * scale;
        im[b0 * CH + co] = (a0 + bias[co]) * scale + base;
        im[b1 * CH + co] = (a1 + bias[co]) * scale + base;
    }
}

// ---------------- K3: fused att + gate (round-5 exact, best known) ----------
// 256-thr block owns (b, 32 positions). thread t: cg = t>>3 (0..31),
// pidx = t&7. Payload x[cg+32j][quad pidx], j=0..23 in registers (whole
// 128B lines per 8-lane group). NT loads (x not cache-reused), NT stores
// (out never re-read; avoids L2 write-allocate churn — R9 showed −45 µs).
__global__ __launch_bounds__(256) void att_gate_kernel(const float* __restrict__ x,
                                                       const float* __restrict__ im,
                                                       float* __restrict__ out) {
    const int b    = blockIdx.y;
    const int p0   = blockIdx.x * 32;                // 32 positions = 8 quads
    const int t    = threadIdx.x;
    const int cg   = t >> 3;                         // 0..31
    const int pidx = t & 7;                          // 0..7

    __shared__ float im_s[CH];
    {
        const fv4* src = (const fv4*)(im + b * CH);
        fv4* dst = (fv4*)im_s;
        for (int i = t; i < CH / 4; i += 256) dst[i] = src[i];
    }

    const float* xb = x + (size_t)b * CH * HW + p0 + pidx * 4;

    fv4 v[24];
    #pragma unroll
    for (int j = 0; j < 24; ++j)
        v[j] = __builtin_nontemporal_load((const fv4*)(xb + (size_t)(cg + 32 * j) * HW));

    __syncthreads();                                 // im_s ready

    fv4 acc = {0.f, 0.f, 0.f, 0.f};
    #pragma unroll
    for (int j = 0; j < 24; ++j)
        acc += im_s[cg + 32 * j] * v[j];

    // intra-wave reduce: lanes 8 apart share pidx
    #pragma unroll
    for (int off = 8; off <= 32; off <<= 1) {
        acc.x += __shfl_down(acc.x, off);
        acc.y += __shfl_down(acc.y, off);
        acc.z += __shfl_down(acc.z, off);
        acc.w += __shfl_down(acc.w, off);
    }
    __shared__ fv4 part[4][8];                       // [wave][pidx]
    __shared__ fv4 att_s[8];
    const int wave = t >> 6, lane = t & 63;
    if (lane < 8) part[wave][lane] = acc;
    __syncthreads();
    if (t < 8) att_s[t] = part[0][t] + part[1][t] + part[2][t] + part[3][t];
    __syncthreads();

    const fv4 a4 = att_s[pidx];
    float* ob = out + (size_t)b * CH * HW + p0 + pidx * 4;
    #pragma unroll
    for (int j = 0; j < 24; ++j)
        __builtin_nontemporal_store(v[j] * a4,
                                    (fv4*)(ob + (size_t)(cg + 32 * j) * HW));
}

extern "C" void kernel_launch(void* const* d_in, const int* in_sizes, int n_in,
                              void* d_out, int out_size, void* d_ws, size_t ws_size,
                              hipStream_t stream) {
    const float* x      = (const float*)d_in[0];
    const float* conv_w = (const float*)d_in[1];
    const float* conv_b = (const float*)d_in[2];
    const float* gamma  = (const float*)d_in[3];
    const float* beta   = (const float*)d_in[4];
    const float* mean   = (const float*)d_in[5];
    const float* var    = (const float*)d_in[6];
    float* out = (float*)d_out;

    float* ws  = (float*)d_ws;
    float* avg = ws;                    // B*C = 24576
    float* mx  = ws + 24576;            // B*C
    float* im  = ws + 49152;            // B*C

    pool_kernel<<<(BATCH * CH) / 4, 256, 0, stream>>>(x, avg, mx);
    mlp_bn_kernel<<<dim3(BATCH / 2, CH / 16), 256, 0, stream>>>(avg, mx, conv_w, conv_b,
                                                                gamma, beta, mean, var, im);
    att_gate_kernel<<<dim3(HW / 32, BATCH), 256, 0, stream>>>(x, im, out);
}